// Round 3
// baseline (73.519 us; speedup 1.0000x reference)
//
#include <hip/hip_runtime.h>

#define EDGE_K 32
#define CAP    128   // per-node candidate cap before serial fallback
#define WPB    4     // waves (nodes) per block

__global__ __launch_bounds__(256) void pack_kernel(
    const float* __restrict__ pos, float4* __restrict__ pk, int n)
{
    int i = blockIdx.x * blockDim.x + threadIdx.x;
    if (i < n) {
        pk[i] = make_float4(pos[3*i+0], pos[3*i+1], pos[3*i+2], 0.0f);
    }
}

template<bool PACKED>
__global__ __launch_bounds__(WPB * 64) void spatial_edge_kernel(
    const float* __restrict__ pos,
    const float4* __restrict__ pk,
    const int* __restrict__ n2g,
    const int* __restrict__ a2r,
    int* __restrict__ out,
    int n)
{
    const int wave = threadIdx.x >> 6;
    const int lane = threadIdx.x & 63;
    const int i    = blockIdx.x * WPB + wave;   // one wave per node
    const bool active = (i < n);

    __shared__ int2 scand[WPB][CAP];     // (bitcast d2, j)
    __shared__ int2 sres[WPB][EDGE_K];   // sorted top-K

    float xi = 0.f, yi = 0.f, zi = 0.f, si = 0.f;
    int ri = 0, jstart = 0, jend = 0;

    if (active) {
        if (PACKED) {
            float4 p = pk[i];
            xi = p.x; yi = p.y; zi = p.z;
        } else {
            xi = pos[3*i+0]; yi = pos[3*i+1]; zi = pos[3*i+2];
        }
        si = xi*xi + yi*yi + zi*zi;
        const int g = n2g[i];
        ri = a2r[i];
        // node2graph sorted -> contiguous same-graph range (uniform search)
        int lo = 0, hi = n;
        while (lo < hi) { int m = (lo + hi) >> 1; if (n2g[m] < g) lo = m + 1; else hi = m; }
        jstart = lo;
        hi = n;
        while (lo < hi) { int m = (lo + hi) >> 1; if (n2g[m] <= g) lo = m + 1; else hi = m; }
        jend = lo;
    }

    // --- parallel scan: lanes stride the candidate range, ballot-compact to LDS
    int count = 0;
    for (int j0 = jstart; j0 < jend; j0 += 64) {
        const int j = j0 + lane;
        bool pass = false;
        float d2 = 0.0f;
        if (j < jend && j != i) {
            float xj, yj, zj;
            if (PACKED) {
                float4 p = pk[j];
                xj = p.x; yj = p.y; zj = p.z;
            } else {
                xj = pos[3*j+0]; yj = pos[3*j+1]; zj = pos[3*j+2];
            }
            const float sj2 = xj*xj + yj*yj + zj*zj;
            const float dt  = xi*xj + yi*yj + zi*zj;
            d2 = si + sj2 - 2.0f*dt;           // exact reference formula
            d2 = fmaxf(d2, 0.0f);
            pass = (d2 <= 25.0f);
        }
        const unsigned long long mask = __ballot(pass);
        if (pass) {
            const int idx = count +
                (int)__builtin_amdgcn_mbcnt_hi((unsigned)(mask >> 32),
                     __builtin_amdgcn_mbcnt_lo((unsigned)mask, 0u));
            if (idx < CAP) scand[wave][idx] = make_int2(__float_as_int(d2), j);
        }
        count += __popcll(mask);
    }
    __syncthreads();

    int cnt = 0;  // number of valid output slots
    if (count <= CAP) {
        // --- rank-based stable sort: rank = #{(d2',j') < (d2,j)} lexicographic
        const int m = count;
        for (int c = lane; c < m; c += 64) {
            const int2 e = scand[wave][c];
            const float dc = __int_as_float(e.x);
            const int   jc = e.y;
            int rank = 0;
            for (int t = 0; t < m; ++t) {
                const int2 et = scand[wave][t];
                const float dtv = __int_as_float(et.x);
                rank += (dtv < dc) || (dtv == dc && et.y < jc);
            }
            if (rank < EDGE_K) sres[wave][rank] = e;
        }
        cnt = (m < EDGE_K) ? m : EDGE_K;
    } else if (active) {
        // --- serial fallback (astronomically rare): lane 0 redoes insertion top-K
        if (lane == 0) {
            float bd[EDGE_K];
            int   bj[EDGE_K];
            int c2 = 0;
            for (int j = jstart; j < jend; ++j) {
                if (j == i) continue;
                float xj, yj, zj;
                if (PACKED) { float4 p = pk[j]; xj = p.x; yj = p.y; zj = p.z; }
                else { xj = pos[3*j+0]; yj = pos[3*j+1]; zj = pos[3*j+2]; }
                const float sj2 = xj*xj + yj*yj + zj*zj;
                const float dt  = xi*xj + yi*yj + zi*zj;
                float d2 = si + sj2 - 2.0f*dt;
                d2 = fmaxf(d2, 0.0f);
                if (d2 > 25.0f) continue;
                if (c2 == EDGE_K && d2 >= bd[EDGE_K-1]) continue;
                int p = (c2 < EDGE_K) ? c2 : (EDGE_K - 1);
                while (p > 0 && bd[p-1] > d2) {
                    bd[p] = bd[p-1]; bj[p] = bj[p-1]; --p;
                }
                bd[p] = d2; bj[p] = j;
                if (c2 < EDGE_K) ++c2;
            }
            for (int k = 0; k < c2; ++k)
                sres[wave][k] = make_int2(__float_as_int(bd[k]), bj[k]);
        }
        cnt = (count < EDGE_K) ? count : EDGE_K;
    }
    __syncthreads();

    // --- epilogue: lanes 0..31 of each wave write one output row each
    const int NK = n * EDGE_K;
    int* valid_out = out + 3 * NK;
    if (active && lane < EDGE_K) {
        const int k = lane;
        int a = -1, b = -1, c = -1, v = 0;
        if (k < cnt) {
            const int j = sres[wave][k].y;
            const int rjres = a2r[j];
            const int rd = (rjres > ri) ? (rjres - ri) : (ri - rjres);
            float xj, yj, zj;
            if (PACKED) { float4 p = pk[j]; xj = p.x; yj = p.y; zj = p.z; }
            else { xj = pos[3*j+0]; yj = pos[3*j+1]; zj = pos[3*j+2]; }
            const float dx = xj - xi;
            const float dy = yj - yi;
            const float dz = zj - zi;
            const float d2s = dx*dx + dy*dy + dz*dz;
            if (rd >= 5 && d2s >= 1e-20f) { a = j; b = i; c = 0; v = 1; }
        }
        const int e = i * EDGE_K + k;
        out[3*e+0] = a;
        out[3*e+1] = b;
        out[3*e+2] = c;
        valid_out[e] = v;
    }
    if (blockIdx.x == 0 && threadIdx.x == 0) out[4*NK] = 1;  // jnp.int32(1)
}

extern "C" void kernel_launch(void* const* d_in, const int* in_sizes, int n_in,
                              void* d_out, int out_size, void* d_ws, size_t ws_size,
                              hipStream_t stream) {
    const float* pos = (const float*)d_in[0];
    const int*   n2g = (const int*)d_in[1];
    const int*   a2r = (const int*)d_in[2];
    int* out = (int*)d_out;
    const int n = in_sizes[0] / 3;
    const int grid = (n + WPB - 1) / WPB;
    const bool packed = (ws_size >= (size_t)n * sizeof(float4)) && (((uintptr_t)d_ws & 15) == 0);
    if (packed) {
        float4* pk = (float4*)d_ws;
        hipLaunchKernelGGL(pack_kernel, dim3((n + 255) / 256), dim3(256), 0, stream,
                           pos, pk, n);
        hipLaunchKernelGGL(spatial_edge_kernel<true>, dim3(grid), dim3(WPB * 64), 0, stream,
                           pos, (const float4*)pk, n2g, a2r, out, n);
    } else {
        hipLaunchKernelGGL(spatial_edge_kernel<false>, dim3(grid), dim3(WPB * 64), 0, stream,
                           pos, (const float4*)nullptr, n2g, a2r, out, n);
    }
}

// Round 4
// 30.030 us; speedup vs baseline: 2.4482x; 2.4482x over previous
//
#include <hip/hip_runtime.h>

#define EDGE_K 32
#define CAP    128   // per-node candidate cap before serial fallback
#define NB     64    // graph-bounds table entries (graph ids must be < NB-1)

// --- pack positions to float4 AND emit graph boundary table (race-free:
// each bounds[g] is written by exactly one thread).
// bounds[g] = first index i with n2g[i] >= g;  bounds[g_last+1..NB-1] = n.
__global__ __launch_bounds__(256) void pack_kernel(
    const float* __restrict__ pos, const int* __restrict__ n2g,
    float4* __restrict__ pk, int* __restrict__ bounds, int n)
{
    int i = blockIdx.x * blockDim.x + threadIdx.x;
    if (i >= n) return;
    pk[i] = make_float4(pos[3*i+0], pos[3*i+1], pos[3*i+2], 0.0f);
    const int gi = n2g[i];
    if (i == 0) {
        for (int g = 0; g <= gi && g < NB; ++g) bounds[g] = 0;
    } else {
        const int gp = n2g[i-1];
        if (gp != gi) for (int g = gp + 1; g <= gi && g < NB; ++g) bounds[g] = i;
    }
    if (i == n - 1) {
        for (int g = gi + 1; g < NB; ++g) bounds[g] = n;
    }
}

// --- fast path: one wave per node, packed float4 loads, 4-deep load pipeline
__global__ __launch_bounds__(64) void spatial_edge_fast(
    const float4* __restrict__ pk,
    const int* __restrict__ n2g,
    const int* __restrict__ a2r,
    const int* __restrict__ bounds,
    int* __restrict__ out, int n)
{
    const int i    = blockIdx.x;
    const int lane = threadIdx.x;

    __shared__ int2 scand[CAP];
    __shared__ int2 sres[EDGE_K];

    const float4 pi = pk[i];
    const float xi = pi.x, yi = pi.y, zi = pi.z;
    const float si = xi*xi + yi*yi + zi*zi;
    const int g  = n2g[i];
    const int ri = a2r[i];

    int jstart, jend;
    if (g < NB - 1) {
        jstart = bounds[g];
        jend   = bounds[g + 1];
    } else {  // defensive: graph id outside table -> binary search (round-2 path)
        int lo = 0, hi = n;
        while (lo < hi) { int m = (lo + hi) >> 1; if (n2g[m] < g) lo = m + 1; else hi = m; }
        jstart = lo; hi = n;
        while (lo < hi) { int m = (lo + hi) >> 1; if (n2g[m] <= g) lo = m + 1; else hi = m; }
        jend = lo;
    }

    int count = 0;
    auto process = [&](float4 p, int j) {
        bool pass = false; float d2 = 0.0f;
        if (j < jend && j != i) {
            const float sj2 = p.x*p.x + p.y*p.y + p.z*p.z;
            const float dt  = xi*p.x + yi*p.y + zi*p.z;
            d2 = si + sj2 - 2.0f*dt;          // exact reference formula
            d2 = fmaxf(d2, 0.0f);
            pass = (d2 <= 25.0f);
        }
        const unsigned long long mask = __ballot(pass);
        if (pass) {
            const int idx = count +
                (int)__builtin_amdgcn_mbcnt_hi((unsigned)(mask >> 32),
                     __builtin_amdgcn_mbcnt_lo((unsigned)mask, 0u));
            if (idx < CAP) scand[idx] = make_int2(__float_as_int(d2), j);
        }
        count += __popcll(mask);
    };

    const int nch = (jend - jstart + 63) >> 6;
    const int jm  = jend - 1;
    for (int c = 0; c < nch; c += 4) {
        const int ja = jstart + (c << 6) + lane;
        // 4 independent loads issued back-to-back (branchless clamped addrs)
        const float4 p0 = pk[min(ja,       jm)];
        const float4 p1 = pk[min(ja +  64, jm)];
        const float4 p2 = pk[min(ja + 128, jm)];
        const float4 p3 = pk[min(ja + 192, jm)];
        process(p0, ja);
        if (c + 1 < nch) process(p1, ja + 64);
        if (c + 2 < nch) process(p2, ja + 128);
        if (c + 3 < nch) process(p3, ja + 192);
    }
    __syncthreads();

    int cnt = 0;
    if (count <= CAP) {
        // rank-based stable sort: rank = #{(d2',j') < (d2,j)} lexicographic
        const int m = count;
        for (int c = lane; c < m; c += 64) {
            const int2 e = scand[c];
            const float dc = __int_as_float(e.x);
            int rank = 0;
            for (int t = 0; t < m; ++t) {
                const int2 et = scand[t];
                const float dtv = __int_as_float(et.x);
                rank += (dtv < dc) || (dtv == dc && et.y < e.y);
            }
            if (rank < EDGE_K) sres[rank] = e;
        }
        cnt = (m < EDGE_K) ? m : EDGE_K;
    } else {
        // serial fallback (astronomically rare): lane 0 insertion top-K
        if (lane == 0) {
            float bd[EDGE_K]; int bj[EDGE_K]; int c2 = 0;
            for (int j = jstart; j < jend; ++j) {
                if (j == i) continue;
                const float4 p = pk[j];
                const float sj2 = p.x*p.x + p.y*p.y + p.z*p.z;
                const float dt  = xi*p.x + yi*p.y + zi*p.z;
                float d2 = si + sj2 - 2.0f*dt;
                d2 = fmaxf(d2, 0.0f);
                if (d2 > 25.0f) continue;
                if (c2 == EDGE_K && d2 >= bd[EDGE_K-1]) continue;
                int p2 = (c2 < EDGE_K) ? c2 : (EDGE_K - 1);
                while (p2 > 0 && bd[p2-1] > d2) { bd[p2] = bd[p2-1]; bj[p2] = bj[p2-1]; --p2; }
                bd[p2] = d2; bj[p2] = j;
                if (c2 < EDGE_K) ++c2;
            }
            for (int k = 0; k < c2; ++k) sres[k] = make_int2(__float_as_int(bd[k]), bj[k]);
        }
        cnt = (count < EDGE_K) ? count : EDGE_K;
    }
    __syncthreads();

    const int NK = n * EDGE_K;
    int* valid_out = out + 3 * NK;
    if (lane < EDGE_K) {
        const int k = lane;
        int a = -1, b = -1, c = -1, v = 0;
        if (k < cnt) {
            const int j = sres[k].y;
            const int rj = a2r[j];
            const int rd = (rj > ri) ? (rj - ri) : (ri - rj);
            const float4 p = pk[j];
            const float dx = p.x - xi, dy = p.y - yi, dz = p.z - zi;
            const float d2s = dx*dx + dy*dy + dz*dz;
            if (rd >= 5 && d2s >= 1e-20f) { a = j; b = i; c = 0; v = 1; }
        }
        const int e = i * EDGE_K + k;
        out[3*e+0] = a;
        out[3*e+1] = b;
        out[3*e+2] = c;
        valid_out[e] = v;
    }
    if (i == 0 && lane == 0) out[4*NK] = 1;   // the jnp.int32(1) scalar output
}

// --- fallback path (ws too small): exact round-2 structure, known-correct
__global__ __launch_bounds__(64) void spatial_edge_ref(
    const float* __restrict__ pos,
    const int* __restrict__ n2g,
    const int* __restrict__ a2r,
    int* __restrict__ out, int n)
{
    const int i = blockIdx.x;
    const int lane = threadIdx.x;
    __shared__ float sd2[CAP]; __shared__ int sj[CAP];
    __shared__ float rd2[EDGE_K]; __shared__ int rjj[EDGE_K];

    const float xi = pos[3*i+0], yi = pos[3*i+1], zi = pos[3*i+2];
    const float si = xi*xi + yi*yi + zi*zi;
    const int g = n2g[i]; const int ri = a2r[i];

    int lo = 0, hi = n;
    while (lo < hi) { int m = (lo + hi) >> 1; if (n2g[m] < g) lo = m + 1; else hi = m; }
    const int jstart = lo; hi = n;
    while (lo < hi) { int m = (lo + hi) >> 1; if (n2g[m] <= g) lo = m + 1; else hi = m; }
    const int jend = lo;

    int count = 0;
    for (int j0 = jstart; j0 < jend; j0 += 64) {
        const int j = j0 + lane;
        bool pass = false; float d2 = 0.0f;
        if (j < jend && j != i) {
            const float xj = pos[3*j+0], yj = pos[3*j+1], zj = pos[3*j+2];
            const float sj2 = xj*xj + yj*yj + zj*zj;
            const float dt  = xi*xj + yi*yj + zi*zj;
            d2 = fmaxf(si + sj2 - 2.0f*dt, 0.0f);
            pass = (d2 <= 25.0f);
        }
        const unsigned long long mask = __ballot(pass);
        if (pass) {
            const int idx = count + __popcll(mask & ((1ull << lane) - 1ull));
            if (idx < CAP) { sd2[idx] = d2; sj[idx] = j; }
        }
        count += __popcll(mask);
    }
    __syncthreads();

    int cnt;
    if (count <= CAP) {
        const int m = count;
        for (int c = lane; c < m; c += 64) {
            const float dc = sd2[c]; const int jc = sj[c];
            int rank = 0;
            for (int t = 0; t < m; ++t)
                rank += (sd2[t] < dc) || (sd2[t] == dc && sj[t] < jc);
            if (rank < EDGE_K) { rd2[rank] = dc; rjj[rank] = jc; }
        }
        cnt = (m < EDGE_K) ? m : EDGE_K;
    } else {
        if (lane == 0) {
            float bd[EDGE_K]; int bj[EDGE_K]; int c2 = 0;
            for (int j = jstart; j < jend; ++j) {
                if (j == i) continue;
                const float xj = pos[3*j+0], yj = pos[3*j+1], zj = pos[3*j+2];
                const float sj2 = xj*xj + yj*yj + zj*zj;
                const float dt  = xi*xj + yi*yj + zi*zj;
                float d2 = fmaxf(si + sj2 - 2.0f*dt, 0.0f);
                if (d2 > 25.0f) continue;
                if (c2 == EDGE_K && d2 >= bd[EDGE_K-1]) continue;
                int p = (c2 < EDGE_K) ? c2 : (EDGE_K - 1);
                while (p > 0 && bd[p-1] > d2) { bd[p] = bd[p-1]; bj[p] = bj[p-1]; --p; }
                bd[p] = d2; bj[p] = j;
                if (c2 < EDGE_K) ++c2;
            }
            for (int k = 0; k < c2; ++k) { rd2[k] = bd[k]; rjj[k] = bj[k]; }
        }
        cnt = (count < EDGE_K) ? count : EDGE_K;
    }
    __syncthreads();

    const int NK = n * EDGE_K;
    int* valid_out = out + 3 * NK;
    if (lane < EDGE_K) {
        const int k = lane;
        int a = -1, b = -1, c = -1, v = 0;
        if (k < cnt) {
            const int j = rjj[k];
            const int rj = a2r[j];
            const int rd = (rj > ri) ? (rj - ri) : (ri - rj);
            const float dx = pos[3*j+0] - xi, dy = pos[3*j+1] - yi, dz = pos[3*j+2] - zi;
            const float d2s = dx*dx + dy*dy + dz*dz;
            if (rd >= 5 && d2s >= 1e-20f) { a = j; b = i; c = 0; v = 1; }
        }
        const int e = i * EDGE_K + k;
        out[3*e+0] = a; out[3*e+1] = b; out[3*e+2] = c;
        valid_out[e] = v;
    }
    if (i == 0 && lane == 0) out[4*NK] = 1;
}

extern "C" void kernel_launch(void* const* d_in, const int* in_sizes, int n_in,
                              void* d_out, int out_size, void* d_ws, size_t ws_size,
                              hipStream_t stream) {
    const float* pos = (const float*)d_in[0];
    const int*   n2g = (const int*)d_in[1];
    const int*   a2r = (const int*)d_in[2];
    int* out = (int*)d_out;
    const int n = in_sizes[0] / 3;
    const size_t need = (size_t)n * sizeof(float4) + NB * sizeof(int);
    const bool packed = (ws_size >= need) && (((uintptr_t)d_ws & 15) == 0);
    if (packed) {
        float4* pk = (float4*)d_ws;
        int* bounds = (int*)(pk + n);
        hipLaunchKernelGGL(pack_kernel, dim3((n + 255) / 256), dim3(256), 0, stream,
                           pos, n2g, pk, bounds, n);
        hipLaunchKernelGGL(spatial_edge_fast, dim3(n), dim3(64), 0, stream,
                           (const float4*)pk, n2g, a2r, (const int*)bounds, out, n);
    } else {
        hipLaunchKernelGGL(spatial_edge_ref, dim3(n), dim3(64), 0, stream,
                           pos, n2g, a2r, out, n);
    }
}

// Round 8
// 29.690 us; speedup vs baseline: 2.4763x; 1.0115x over previous
//
#include <hip/hip_runtime.h>

#define EDGE_K 32
#define CAP    128   // per-node candidate cap before serial fallback
#define NB     64    // graph-bounds table entries (graph ids must be < NB-1)

// --- pack positions to float4 AND emit graph boundary table (race-free:
// each bounds[g] is written by exactly one thread).
// bounds[g] = first index i with n2g[i] >= g;  bounds[g_last+1..NB-1] = n.
__global__ __launch_bounds__(256) void pack_kernel(
    const float* __restrict__ pos, const int* __restrict__ n2g,
    float4* __restrict__ pk, int* __restrict__ bounds, int n)
{
    int i = blockIdx.x * blockDim.x + threadIdx.x;
    if (i >= n) return;
    pk[i] = make_float4(pos[3*i+0], pos[3*i+1], pos[3*i+2], 0.0f);
    const int gi = n2g[i];
    if (i == 0) {
        for (int g = 0; g <= gi && g < NB; ++g) bounds[g] = 0;
    } else {
        const int gp = n2g[i-1];
        if (gp != gi) for (int g = gp + 1; g <= gi && g < NB; ++g) bounds[g] = i;
    }
    if (i == n - 1) {
        for (int g = gi + 1; g < NB; ++g) bounds[g] = n;
    }
}

// --- fast path: one wave per node, packed float4 loads, 4-deep load pipeline
__global__ __launch_bounds__(64) void spatial_edge_fast(
    const float4* __restrict__ pk,
    const int* __restrict__ n2g,
    const int* __restrict__ a2r,
    const int* __restrict__ bounds,
    int* __restrict__ out, int n)
{
    const int i    = blockIdx.x;
    const int lane = threadIdx.x;

    __shared__ int2 scand[CAP];
    __shared__ int2 sres[EDGE_K];

    const float4 pi = pk[i];
    const float xi = pi.x, yi = pi.y, zi = pi.z;
    const float si = xi*xi + yi*yi + zi*zi;
    const int g  = n2g[i];
    const int ri = a2r[i];

    int jstart, jend;
    if (g < NB - 1) {
        jstart = bounds[g];
        jend   = bounds[g + 1];
    } else {  // defensive: graph id outside table -> binary search (round-2 path)
        int lo = 0, hi = n;
        while (lo < hi) { int m = (lo + hi) >> 1; if (n2g[m] < g) lo = m + 1; else hi = m; }
        jstart = lo; hi = n;
        while (lo < hi) { int m = (lo + hi) >> 1; if (n2g[m] <= g) lo = m + 1; else hi = m; }
        jend = lo;
    }

    int count = 0;
    auto process = [&](float4 p, int j) {
        bool pass = false; float d2 = 0.0f;
        if (j < jend && j != i) {
            const float sj2 = p.x*p.x + p.y*p.y + p.z*p.z;
            const float dt  = xi*p.x + yi*p.y + zi*p.z;
            d2 = si + sj2 - 2.0f*dt;          // exact reference formula
            d2 = fmaxf(d2, 0.0f);
            pass = (d2 <= 25.0f);
        }
        const unsigned long long mask = __ballot(pass);
        if (pass) {
            const int idx = count +
                (int)__builtin_amdgcn_mbcnt_hi((unsigned)(mask >> 32),
                     __builtin_amdgcn_mbcnt_lo((unsigned)mask, 0u));
            if (idx < CAP) scand[idx] = make_int2(__float_as_int(d2), j);
        }
        count += __popcll(mask);
    };

    const int nch = (jend - jstart + 63) >> 6;
    const int jm  = jend - 1;
    for (int c = 0; c < nch; c += 4) {
        const int ja = jstart + (c << 6) + lane;
        // 4 independent loads issued back-to-back (branchless clamped addrs)
        const float4 p0 = pk[min(ja,       jm)];
        const float4 p1 = pk[min(ja +  64, jm)];
        const float4 p2 = pk[min(ja + 128, jm)];
        const float4 p3 = pk[min(ja + 192, jm)];
        process(p0, ja);
        if (c + 1 < nch) process(p1, ja + 64);
        if (c + 2 < nch) process(p2, ja + 128);
        if (c + 3 < nch) process(p3, ja + 192);
    }
    __syncthreads();

    int cnt = 0;
    if (count <= CAP) {
        // rank-based stable sort: rank = #{(d2',j') < (d2,j)} lexicographic
        const int m = count;
        for (int c = lane; c < m; c += 64) {
            const int2 e = scand[c];
            const float dc = __int_as_float(e.x);
            int rank = 0;
            for (int t = 0; t < m; ++t) {
                const int2 et = scand[t];
                const float dtv = __int_as_float(et.x);
                rank += (dtv < dc) || (dtv == dc && et.y < e.y);
            }
            if (rank < EDGE_K) sres[rank] = e;
        }
        cnt = (m < EDGE_K) ? m : EDGE_K;
    } else {
        // serial fallback (astronomically rare): lane 0 insertion top-K
        if (lane == 0) {
            float bd[EDGE_K]; int bj[EDGE_K]; int c2 = 0;
            for (int j = jstart; j < jend; ++j) {
                if (j == i) continue;
                const float4 p = pk[j];
                const float sj2 = p.x*p.x + p.y*p.y + p.z*p.z;
                const float dt  = xi*p.x + yi*p.y + zi*p.z;
                float d2 = si + sj2 - 2.0f*dt;
                d2 = fmaxf(d2, 0.0f);
                if (d2 > 25.0f) continue;
                if (c2 == EDGE_K && d2 >= bd[EDGE_K-1]) continue;
                int p2 = (c2 < EDGE_K) ? c2 : (EDGE_K - 1);
                while (p2 > 0 && bd[p2-1] > d2) { bd[p2] = bd[p2-1]; bj[p2] = bj[p2-1]; --p2; }
                bd[p2] = d2; bj[p2] = j;
                if (c2 < EDGE_K) ++c2;
            }
            for (int k = 0; k < c2; ++k) sres[k] = make_int2(__float_as_int(bd[k]), bj[k]);
        }
        cnt = (count < EDGE_K) ? count : EDGE_K;
    }
    __syncthreads();

    const int NK = n * EDGE_K;
    int* valid_out = out + 3 * NK;
    if (lane < EDGE_K) {
        const int k = lane;
        int a = -1, b = -1, c = -1, v = 0;
        if (k < cnt) {
            const int j = sres[k].y;
            const int rj = a2r[j];
            const int rd = (rj > ri) ? (rj - ri) : (ri - rj);
            const float4 p = pk[j];
            const float dx = p.x - xi, dy = p.y - yi, dz = p.z - zi;
            const float d2s = dx*dx + dy*dy + dz*dz;
            if (rd >= 5 && d2s >= 1e-20f) { a = j; b = i; c = 0; v = 1; }
        }
        const int e = i * EDGE_K + k;
        out[3*e+0] = a;
        out[3*e+1] = b;
        out[3*e+2] = c;
        valid_out[e] = v;
    }
    if (i == 0 && lane == 0) out[4*NK] = 1;   // the jnp.int32(1) scalar output
}

// --- fallback path (ws too small): exact round-2 structure, known-correct
__global__ __launch_bounds__(64) void spatial_edge_ref(
    const float* __restrict__ pos,
    const int* __restrict__ n2g,
    const int* __restrict__ a2r,
    int* __restrict__ out, int n)
{
    const int i = blockIdx.x;
    const int lane = threadIdx.x;
    __shared__ float sd2[CAP]; __shared__ int sj[CAP];
    __shared__ float rd2[EDGE_K]; __shared__ int rjj[EDGE_K];

    const float xi = pos[3*i+0], yi = pos[3*i+1], zi = pos[3*i+2];
    const float si = xi*xi + yi*yi + zi*zi;
    const int g = n2g[i]; const int ri = a2r[i];

    int lo = 0, hi = n;
    while (lo < hi) { int m = (lo + hi) >> 1; if (n2g[m] < g) lo = m + 1; else hi = m; }
    const int jstart = lo; hi = n;
    while (lo < hi) { int m = (lo + hi) >> 1; if (n2g[m] <= g) lo = m + 1; else hi = m; }
    const int jend = lo;

    int count = 0;
    for (int j0 = jstart; j0 < jend; j0 += 64) {
        const int j = j0 + lane;
        bool pass = false; float d2 = 0.0f;
        if (j < jend && j != i) {
            const float xj = pos[3*j+0], yj = pos[3*j+1], zj = pos[3*j+2];
            const float sj2 = xj*xj + yj*yj + zj*zj;
            const float dt  = xi*xj + yi*yj + zi*zj;
            d2 = fmaxf(si + sj2 - 2.0f*dt, 0.0f);
            pass = (d2 <= 25.0f);
        }
        const unsigned long long mask = __ballot(pass);
        if (pass) {
            const int idx = count + __popcll(mask & ((1ull << lane) - 1ull));
            if (idx < CAP) { sd2[idx] = d2; sj[idx] = j; }
        }
        count += __popcll(mask);
    }
    __syncthreads();

    int cnt;
    if (count <= CAP) {
        const int m = count;
        for (int c = lane; c < m; c += 64) {
            const float dc = sd2[c]; const int jc = sj[c];
            int rank = 0;
            for (int t = 0; t < m; ++t)
                rank += (sd2[t] < dc) || (sd2[t] == dc && sj[t] < jc);
            if (rank < EDGE_K) { rd2[rank] = dc; rjj[rank] = jc; }
        }
        cnt = (m < EDGE_K) ? m : EDGE_K;
    } else {
        if (lane == 0) {
            float bd[EDGE_K]; int bj[EDGE_K]; int c2 = 0;
            for (int j = jstart; j < jend; ++j) {
                if (j == i) continue;
                const float xj = pos[3*j+0], yj = pos[3*j+1], zj = pos[3*j+2];
                const float sj2 = xj*xj + yj*yj + zj*zj;
                const float dt  = xi*xj + yi*yj + zi*zj;
                float d2 = fmaxf(si + sj2 - 2.0f*dt, 0.0f);
                if (d2 > 25.0f) continue;
                if (c2 == EDGE_K && d2 >= bd[EDGE_K-1]) continue;
                int p = (c2 < EDGE_K) ? c2 : (EDGE_K - 1);
                while (p > 0 && bd[p-1] > d2) { bd[p] = bd[p-1]; bj[p] = bj[p-1]; --p; }
                bd[p] = d2; bj[p] = j;
                if (c2 < EDGE_K) ++c2;
            }
            for (int k = 0; k < c2; ++k) { rd2[k] = bd[k]; rjj[k] = bj[k]; }
        }
        cnt = (count < EDGE_K) ? count : EDGE_K;
    }
    __syncthreads();

    const int NK = n * EDGE_K;
    int* valid_out = out + 3 * NK;
    if (lane < EDGE_K) {
        const int k = lane;
        int a = -1, b = -1, c = -1, v = 0;
        if (k < cnt) {
            const int j = rjj[k];
            const int rj = a2r[j];
            const int rd = (rj > ri) ? (rj - ri) : (ri - rj);
            const float dx = pos[3*j+0] - xi, dy = pos[3*j+1] - yi, dz = pos[3*j+2] - zi;
            const float d2s = dx*dx + dy*dy + dz*dz;
            if (rd >= 5 && d2s >= 1e-20f) { a = j; b = i; c = 0; v = 1; }
        }
        const int e = i * EDGE_K + k;
        out[3*e+0] = a; out[3*e+1] = b; out[3*e+2] = c;
        valid_out[e] = v;
    }
    if (i == 0 && lane == 0) out[4*NK] = 1;
}

extern "C" void kernel_launch(void* const* d_in, const int* in_sizes, int n_in,
                              void* d_out, int out_size, void* d_ws, size_t ws_size,
                              hipStream_t stream) {
    const float* pos = (const float*)d_in[0];
    const int*   n2g = (const int*)d_in[1];
    const int*   a2r = (const int*)d_in[2];
    int* out = (int*)d_out;
    const int n = in_sizes[0] / 3;
    const size_t need = (size_t)n * sizeof(float4) + NB * sizeof(int);
    const bool packed = (ws_size >= need) && (((uintptr_t)d_ws & 15) == 0);
    if (packed) {
        float4* pk = (float4*)d_ws;
        int* bounds = (int*)(pk + n);
        hipLaunchKernelGGL(pack_kernel, dim3((n + 255) / 256), dim3(256), 0, stream,
                           pos, n2g, pk, bounds, n);
        hipLaunchKernelGGL(spatial_edge_fast, dim3(n), dim3(64), 0, stream,
                           (const float4*)pk, n2g, a2r, (const int*)bounds, out, n);
    } else {
        hipLaunchKernelGGL(spatial_edge_ref, dim3(n), dim3(64), 0, stream,
                           pos, n2g, a2r, out, n);
    }
}